// Round 3
// baseline (116.994 us; speedup 1.0000x reference)
//
#include <hip/hip_runtime.h>
#include <float.h>

#define NCNT 33   // count classes 0..32
#define NPTS 32   // max poles/zeros

typedef float f32x2 __attribute__((ext_vector_type(2)));

__device__ __forceinline__ f32x2 mk2(float a, float b) { f32x2 r; r.x = a; r.y = b; return r; }

// ---------- DPP helpers ----------
template<int CTRL, bool BC>
__device__ __forceinline__ int dpp_i(int old, int v) {
    return __builtin_amdgcn_update_dpp(old, v, CTRL, 0xF, 0xF, BC);
}

// Dual full-wave (64) sum; results broadcast via readlane 63.
// Per-value op sequence identical to the single version (bitwise-preserving);
// the two chains are independent -> dual-issue latency hiding.
__device__ __forceinline__ void wave_sum63x2(float& va, float& vb) {
#define SUM_STEP(C)                                                          \
    va += __int_as_float(dpp_i<C, true>(0, __float_as_int(va)));             \
    vb += __int_as_float(dpp_i<C, true>(0, __float_as_int(vb)));
    SUM_STEP(0x111) SUM_STEP(0x112) SUM_STEP(0x114) SUM_STEP(0x118) SUM_STEP(0x142) SUM_STEP(0x143)
#undef SUM_STEP
    va = __int_as_float(__builtin_amdgcn_readlane(__float_as_int(va), 63));
    vb = __int_as_float(__builtin_amdgcn_readlane(__float_as_int(vb), 63));
}

// Dual full-wave max; bound_ctrl=false + old=v so invalid sources give fmax(v,v)=v.
__device__ __forceinline__ void wave_max63x2(float& va, float& vb) {
#define MX_STEP(C)                                                                    \
    {                                                                                 \
        int oa = dpp_i<C, false>(__float_as_int(va), __float_as_int(va));             \
        int ob = dpp_i<C, false>(__float_as_int(vb), __float_as_int(vb));             \
        va = fmaxf(va, __int_as_float(oa));                                           \
        vb = fmaxf(vb, __int_as_float(ob));                                           \
    }
    MX_STEP(0x111) MX_STEP(0x112) MX_STEP(0x114) MX_STEP(0x118) MX_STEP(0x142) MX_STEP(0x143)
#undef MX_STEP
    va = __int_as_float(__builtin_amdgcn_readlane(__float_as_int(va), 63));
    vb = __int_as_float(__builtin_amdgcn_readlane(__float_as_int(vb), 63));
}

// ---------- main kernel: each wave handles one ROW = 2 units (pole part A, zero part B) ----------
// Per-wave LDS: two 192-float slices (A then B). Slice layout unchanged from round 2:
// tgt UV [0..63], tgt S [64..95], pred UV [96..159], pred S [160..191].
// UV float4 j = (u_{2j}, u_{2j+1}, v_{2j}, v_{2j+1}); u=-2x, v=-2y, s=|pt|^2 (1e30 invalid).
// All per-unit arithmetic is op-for-op identical to the previous version; the A/B chains
// are interleaved purely for ILP (the kernel was latency-bound on serial DPP chains).
__global__ __launch_bounds__(256) void vltf_kernel(
    const float* __restrict__ pole_logits, const float* __restrict__ zero_logits,
    const float* __restrict__ poles_all,   const float* __restrict__ zeros_all,
    const float* __restrict__ tpoles,      const float* __restrict__ tzeros,
    const int* __restrict__ tnum_p,        const int* __restrict__ tnum_z,
    float* __restrict__ partials)
{
    __shared__ __align__(16) float lds[4 * 384];

    const int lane = threadIdx.x & 63;          // 0..63 within wave
    const int wid  = threadIdx.x >> 6;          // wave 0..3
    const int row  = (blockIdx.x << 2) | wid;   // one row per wave; B divisible by 4
    float* mylA = lds + wid * 384;              // unit A = (row, pole)
    float* mylB = mylA + 192;                   // unit B = (row, zero)

    // ---- cross-entropy + argmax over 33 logits, dual ----
    float xA = (lane < NCNT) ? pole_logits[row * NCNT + lane] : -FLT_MAX;
    float xB = (lane < NCNT) ? zero_logits[row * NCNT + lane] : -FLT_MAX;
    float vmaxA = xA, vmaxB = xB;
    wave_max63x2(vmaxA, vmaxB);
    unsigned long long bmA = __ballot(lane < NCNT && xA == vmaxA);
    unsigned long long bmB = __ballot(lane < NCNT && xB == vmaxB);
    const int npA = (int)__builtin_ctzll(bmA);   // pred pole count (uniform)
    const int npB = (int)__builtin_ctzll(bmB);   // pred zero count (uniform)
    float eA = (lane < NCNT) ? __expf(xA - vmaxA) : 0.f;
    float eB = (lane < NCNT) ? __expf(xB - vmaxB) : 0.f;
    float sumeA = eA, sumeB = eB;
    wave_sum63x2(sumeA, sumeB);
    const int ntA = tnum_p[row];                 // target counts (uniform)
    const int ntB = tnum_z[row];
    float xtA = __int_as_float(__builtin_amdgcn_readlane(__float_as_int(xA), ntA));
    float xtB = __int_as_float(__builtin_amdgcn_readlane(__float_as_int(xB), ntB));
    float nllA = vmaxA + __logf(sumeA) - xtA;
    float nllB = vmaxB + __logf(sumeB) - xtB;

    // ---- load own points; stage (u,v,s) for the other half, dual ----
    const bool isPred = lane < 32;
    const int  idx    = lane & 31;
    const float2* ownA = (const float2*)(isPred ? poles_all : tpoles);
    const float2* ownB = (const float2*)(isPred ? zeros_all : tzeros);
    const float2  PtA  = ownA[row * NPTS + idx];
    const float2  PtB  = ownB[row * NPTS + idx];
    const int  nownA = isPred ? npA : ntA;
    const int  nownB = isPred ? npB : ntB;
    const bool vownA = idx < nownA;
    const bool vownB = idx < nownB;
    const float srealA = fmaf(PtA.x, PtA.x, PtA.y * PtA.y);
    const float srealB = fmaf(PtB.x, PtB.x, PtB.y * PtB.y);

    const int wbase = isPred ? 96 : 0;
    const int uvpos = wbase + ((idx >> 1) << 2) + (idx & 1);
    mylA[uvpos]            = vownA ? -2.f * PtA.x : 0.f;
    mylA[uvpos + 2]        = vownA ? -2.f * PtA.y : 0.f;
    mylA[wbase + 64 + idx] = vownA ? srealA : 1e30f;
    mylB[uvpos]            = vownB ? -2.f * PtB.x : 0.f;
    mylB[uvpos + 2]        = vownB ? -2.f * PtB.y : 0.f;
    mylB[wbase + 64 + idx] = vownB ? srealB : 1e30f;
    __syncthreads();   // orders LDS write->read; cheap 4-wave rendezvous

    // ---- chamfer: min over 32 "other" points, dual, 4 points/unit/iter via pk_fma ----
    const int rbase = isPred ? 0 : 96;            // pred lanes read tgt staging, vice versa
    const float4* UVoA = (const float4*)(mylA + rbase);
    const float4* SoA  = (const float4*)(mylA + rbase + 64);
    const float4* UVoB = (const float4*)(mylB + rbase);
    const float4* SoB  = (const float4*)(mylB + rbase + 64);
    const f32x2 PxvA = mk2(PtA.x, PtA.x), PyvA = mk2(PtA.y, PtA.y);
    const f32x2 PxvB = mk2(PtB.x, PtB.x), PyvB = mk2(PtB.y, PtB.y);
    float mA = FLT_MAX, mB = FLT_MAX;
#pragma unroll
    for (int i = 0; i < 8; ++i) {
        float4 uv0A = UVoA[2 * i], uv1A = UVoA[2 * i + 1];
        float4 s4A  = SoA[i];
        float4 uv0B = UVoB[2 * i], uv1B = UVoB[2 * i + 1];
        float4 s4B  = SoB[i];
        f32x2 val0A = PyvA * mk2(uv0A.z, uv0A.w) + mk2(s4A.x, s4A.y);
        val0A       = PxvA * mk2(uv0A.x, uv0A.y) + val0A;
        f32x2 val0B = PyvB * mk2(uv0B.z, uv0B.w) + mk2(s4B.x, s4B.y);
        val0B       = PxvB * mk2(uv0B.x, uv0B.y) + val0B;
        f32x2 val1A = PyvA * mk2(uv1A.z, uv1A.w) + mk2(s4A.z, s4A.w);
        val1A       = PxvA * mk2(uv1A.x, uv1A.y) + val1A;
        f32x2 val1B = PyvB * mk2(uv1B.z, uv1B.w) + mk2(s4B.z, s4B.w);
        val1B       = PxvB * mk2(uv1B.x, uv1B.y) + val1B;
        mA = fminf(mA, fminf(val0A.x, val0A.y));  // v_min3_f32
        mB = fminf(mB, fminf(val0B.x, val0B.y));
        mA = fminf(mA, fminf(val1A.x, val1A.y));
        mB = fminf(mB, fminf(val1B.x, val1B.y));
    }

    // ---- per-lane terms with wave-uniform special cases, dual ----
    float TA;
    if (npA > 0 && ntA > 0) {
        float inv_n = __builtin_amdgcn_rcpf((float)nownA);
        TA = vownA ? (mA + srealA) * inv_n : 0.f;
    } else if (npA == 0 && ntA == 0) {
        TA = 0.f;
    } else if (npA == 0) {
        TA = (!isPred && vownA) ? srealA : 0.f;
    } else {
        TA = (isPred && vownA) ? srealA : 0.f;
    }
    float TB;
    if (npB > 0 && ntB > 0) {
        float inv_n = __builtin_amdgcn_rcpf((float)nownB);
        TB = vownB ? (mB + srealB) * inv_n : 0.f;
    } else if (npB == 0 && ntB == 0) {
        TB = 0.f;
    } else if (npB == 0) {
        TB = (!isPred && vownB) ? srealB : 0.f;
    } else {
        TB = (isPred && vownB) ? srealB : 0.f;
    }
    float chamA = TA, chamB = TB;
    wave_sum63x2(chamA, chamB);

    if (lane == 0) {
        float2 out2; out2.x = 5.f * nllA + chamA; out2.y = 5.f * nllB + chamB;
        ((float2*)partials)[row] = out2;          // partials[2*row], partials[2*row+1]
    }
}

// ---------- finalize: sum 65536 partials (as 16384 float4), divide by B ----------
__device__ __forceinline__ float wave_sum63(float v) {
    v += __int_as_float(dpp_i<0x111, true>(0, __float_as_int(v)));
    v += __int_as_float(dpp_i<0x112, true>(0, __float_as_int(v)));
    v += __int_as_float(dpp_i<0x114, true>(0, __float_as_int(v)));
    v += __int_as_float(dpp_i<0x118, true>(0, __float_as_int(v)));
    v += __int_as_float(dpp_i<0x142, true>(0, __float_as_int(v)));
    v += __int_as_float(dpp_i<0x143, true>(0, __float_as_int(v)));
    return __int_as_float(__builtin_amdgcn_readlane(__float_as_int(v), 63));
}

__global__ __launch_bounds__(1024) void vltf_finalize(
    const float4* __restrict__ p4, int n4, float invB, float* __restrict__ out)
{
    float s = 0.f;
    for (int i = threadIdx.x; i < n4; i += 1024) {
        float4 v = p4[i];
        s += (v.x + v.y) + (v.z + v.w);
    }
    s = wave_sum63(s);
    __shared__ float sh[16];
    if ((threadIdx.x & 63) == 0) sh[threadIdx.x >> 6] = s;
    __syncthreads();
    if (threadIdx.x == 0) {
        float t = 0.f;
#pragma unroll
        for (int i = 0; i < 16; ++i) t += sh[i];
        out[0] = t * invB;
    }
}

extern "C" void kernel_launch(void* const* d_in, const int* in_sizes, int n_in,
                              void* d_out, int out_size, void* d_ws, size_t ws_size,
                              hipStream_t stream) {
    const float* pole_logits = (const float*)d_in[0];
    const float* zero_logits = (const float*)d_in[1];
    const float* poles_all   = (const float*)d_in[2];
    const float* zeros_all   = (const float*)d_in[3];
    const float* tpoles      = (const float*)d_in[4];
    const float* tzeros      = (const float*)d_in[5];
    const int*   tnp         = (const int*)d_in[6];
    const int*   tnz         = (const int*)d_in[7];

    const int B     = in_sizes[6];       // 32768
    const int units = 2 * B;             // partials count (one float2 per row)

    float* partials = (float*)d_ws;      // units * 4 bytes (256 KiB) of scratch

    vltf_kernel<<<B / 4, 256, 0, stream>>>(pole_logits, zero_logits,
                                           poles_all, zeros_all,
                                           tpoles, tzeros, tnp, tnz, partials);
    vltf_finalize<<<1, 1024, 0, stream>>>((const float4*)partials, units / 4,
                                          1.0f / (float)B, (float*)d_out);
}

// Round 4
// 113.107 us; speedup vs baseline: 1.0344x; 1.0344x over previous
//
#include <hip/hip_runtime.h>
#include <float.h>

#define NCNT 33   // count classes 0..32
#define NPTS 32   // max poles/zeros

typedef float f32x2 __attribute__((ext_vector_type(2)));

__device__ __forceinline__ f32x2 mk2(float a, float b) { f32x2 r; r.x = a; r.y = b; return r; }

// ---------- DPP helpers ----------
template<int CTRL, bool BC>
__device__ __forceinline__ int dpp_i(int old, int v) {
    return __builtin_amdgcn_update_dpp(old, v, CTRL, 0xF, 0xF, BC);
}

// full-wave (64) sum; result broadcast to all lanes via readlane 63
__device__ __forceinline__ float wave_sum63(float v) {
    v += __int_as_float(dpp_i<0x111, true>(0, __float_as_int(v))); // row_shr:1
    v += __int_as_float(dpp_i<0x112, true>(0, __float_as_int(v))); // row_shr:2
    v += __int_as_float(dpp_i<0x114, true>(0, __float_as_int(v))); // row_shr:4
    v += __int_as_float(dpp_i<0x118, true>(0, __float_as_int(v))); // row_shr:8
    v += __int_as_float(dpp_i<0x142, true>(0, __float_as_int(v))); // row_bcast:15
    v += __int_as_float(dpp_i<0x143, true>(0, __float_as_int(v))); // row_bcast:31
    return __int_as_float(__builtin_amdgcn_readlane(__float_as_int(v), 63));
}

// full-wave max; result broadcast (uniform). bound_ctrl=false + old=v so
// out-of-range source lanes contribute fmax(v,v)=v.
__device__ __forceinline__ float wave_max63(float v) {
#define MX_STEP(C)                                                                    \
    {                                                                                 \
        int o = dpp_i<C, false>(__float_as_int(v), __float_as_int(v));                \
        v = fmaxf(v, __int_as_float(o));                                              \
    }
    MX_STEP(0x111) MX_STEP(0x112) MX_STEP(0x114) MX_STEP(0x118) MX_STEP(0x142) MX_STEP(0x143)
#undef MX_STEP
    return __int_as_float(__builtin_amdgcn_readlane(__float_as_int(v), 63));
}

// ---------- main kernel: persistent waves, grid-stride over units, prefetched ----------
// Each wave owns a private 192-float LDS slice (written and read ONLY by itself ->
// no __syncthreads; intra-wave LDS RAW is ordered by lgkmcnt). Wave w handles units
// {w, w+W, w+2W, ...}; W is even so each wave's part (pole/zero) is loop-invariant.
// Next unit's global loads are issued before current unit's compute (latency hiding).
// Per-unit arithmetic is op-for-op identical to the previous version (bitwise-same).
// Slice layout: tgt UV [0..63], tgt S [64..95], pred UV [96..159], pred S [160..191].
// UV float4 j = (u_{2j}, u_{2j+1}, v_{2j}, v_{2j+1}); u=-2x, v=-2y, s=|pt|^2 (1e30 invalid).
__global__ __launch_bounds__(256) void vltf_kernel(
    const float* __restrict__ pole_logits, const float* __restrict__ zero_logits,
    const float* __restrict__ poles_all,   const float* __restrict__ zeros_all,
    const float* __restrict__ tpoles,      const float* __restrict__ tzeros,
    const int* __restrict__ tnum_p,        const int* __restrict__ tnum_z,
    float* __restrict__ partials, int B)
{
    __shared__ __align__(16) float lds[4 * 192];

    const int lane = threadIdx.x & 63;          // 0..63 within wave
    const int wid  = threadIdx.x >> 6;          // wave 0..3
    const int w    = (blockIdx.x << 2) | wid;   // global wave id
    const int W    = gridDim.x << 2;            // total waves (even)
    float* myl = lds + wid * 192;               // private per-wave slice

    const int  part   = w & 1;                  // loop-invariant part for this wave
    const bool isPred = lane < 32;
    const int  idx    = lane & 31;

    const float* logits  = part ? zero_logits : pole_logits;
    const float2* ownArr = (const float2*)(part ? (isPred ? zeros_all : tzeros)
                                                : (isPred ? poles_all : tpoles));
    const int* tnum      = part ? tnum_z : tnum_p;

    const int r0      = w >> 1;                 // first row for this wave
    const int rstride = W >> 1;                 // row stride per iteration
    if (r0 >= B) return;

    // ---- prefetch first unit ----
    float  x_n  = (lane < NCNT) ? logits[r0 * NCNT + lane] : -FLT_MAX;
    float2 Pt_n = ownArr[r0 * NPTS + idx];
    int    nt_n = tnum[r0];

    for (int r = r0; r < B; r += rstride) {
        const float  x  = x_n;
        const float2 Pt = Pt_n;
        const int    nt = nt_n;                 // target count (uniform)

        // ---- issue next unit's loads; consumed next iteration (latency hidden) ----
        const int rn = r + rstride;
        if (rn < B) {
            x_n  = (lane < NCNT) ? logits[rn * NCNT + lane] : -FLT_MAX;
            Pt_n = ownArr[rn * NPTS + idx];
            nt_n = tnum[rn];
        }

        // ---- cross-entropy + argmax over 33 logits (lanes 0..32 active) ----
        float vmax = wave_max63(x);
        unsigned long long bm = __ballot(lane < NCNT && x == vmax);
        const int np = (int)__builtin_ctzll(bm);   // first-max index == pred count (uniform)
        float e = (lane < NCNT) ? __expf(x - vmax) : 0.f;
        float sume = wave_sum63(e);
        float xt = __int_as_float(__builtin_amdgcn_readlane(__float_as_int(x), nt));
        float nll = vmax + __logf(sume) - xt;

        // ---- stage (u,v,s) for the other half (own slice only) ----
        const int  nown  = isPred ? np : nt;
        const bool vown  = idx < nown;
        const float sreal = fmaf(Pt.x, Pt.x, Pt.y * Pt.y);

        const int wbase = isPred ? 96 : 0;
        const int uvpos = wbase + ((idx >> 1) << 2) + (idx & 1);
        myl[uvpos]            = vown ? -2.f * Pt.x : 0.f;
        myl[uvpos + 2]        = vown ? -2.f * Pt.y : 0.f;
        myl[wbase + 64 + idx] = vown ? sreal : 1e30f;
        // no barrier: same-wave LDS write->read ordered by lgkmcnt

        // ---- chamfer: min over 32 "other" points, 4 points/iter via pk_fma ----
        const int rbase = isPred ? 0 : 96;
        const float4* UVo = (const float4*)(myl + rbase);
        const float4* So  = (const float4*)(myl + rbase + 64);
        const f32x2 Pxv = mk2(Pt.x, Pt.x);
        const f32x2 Pyv = mk2(Pt.y, Pt.y);
        float m = FLT_MAX;
#pragma unroll
        for (int i = 0; i < 8; ++i) {
            float4 uv0 = UVo[2 * i], uv1 = UVo[2 * i + 1];
            float4 s4  = So[i];
            f32x2 val0 = Pyv * mk2(uv0.z, uv0.w) + mk2(s4.x, s4.y);
            val0       = Pxv * mk2(uv0.x, uv0.y) + val0;
            f32x2 val1 = Pyv * mk2(uv1.z, uv1.w) + mk2(s4.z, s4.w);
            val1       = Pxv * mk2(uv1.x, uv1.y) + val1;
            m = fminf(m, fminf(val0.x, val0.y));  // v_min3_f32
            m = fminf(m, fminf(val1.x, val1.y));
        }

        // ---- per-lane term with wave-uniform special cases ----
        float T;
        if (np > 0 && nt > 0) {
            float inv_n = __builtin_amdgcn_rcpf((float)nown);
            T = vown ? (m + sreal) * inv_n : 0.f;  // |p|^2 folded in once
        } else if (np == 0 && nt == 0) {
            T = 0.f;
        } else if (np == 0) {                       // out = sum_tgt_sq
            T = (!isPred && vown) ? sreal : 0.f;
        } else {                                    // nt == 0 -> sum_pred_sq
            T = (isPred && vown) ? sreal : 0.f;
        }
        float cham = wave_sum63(T);

        if (lane == 0) partials[2 * r + part] = 5.f * nll + cham;
    }
}

// ---------- finalize: sum 65536 partials (as 16384 float4), divide by B ----------
__global__ __launch_bounds__(1024) void vltf_finalize(
    const float4* __restrict__ p4, int n4, float invB, float* __restrict__ out)
{
    float s = 0.f;
    for (int i = threadIdx.x; i < n4; i += 1024) {
        float4 v = p4[i];
        s += (v.x + v.y) + (v.z + v.w);
    }
    s = wave_sum63(s);
    __shared__ float sh[16];
    if ((threadIdx.x & 63) == 0) sh[threadIdx.x >> 6] = s;
    __syncthreads();
    if (threadIdx.x == 0) {
        float t = 0.f;
#pragma unroll
        for (int i = 0; i < 16; ++i) t += sh[i];
        out[0] = t * invB;
    }
}

extern "C" void kernel_launch(void* const* d_in, const int* in_sizes, int n_in,
                              void* d_out, int out_size, void* d_ws, size_t ws_size,
                              hipStream_t stream) {
    const float* pole_logits = (const float*)d_in[0];
    const float* zero_logits = (const float*)d_in[1];
    const float* poles_all   = (const float*)d_in[2];
    const float* zeros_all   = (const float*)d_in[3];
    const float* tpoles      = (const float*)d_in[4];
    const float* tzeros      = (const float*)d_in[5];
    const int*   tnp         = (const int*)d_in[6];
    const int*   tnz         = (const int*)d_in[7];

    const int B     = in_sizes[6];       // 32768
    const int units = 2 * B;

    float* partials = (float*)d_ws;      // units * 4 bytes (256 KiB) of scratch

    // persistent waves: 2048 blocks x 4 waves = 8192 waves (8/SIMD), 8 units/wave
    int blocks = 2048;
    if (blocks * 4 > units) blocks = (units + 3) / 4;
    vltf_kernel<<<blocks, 256, 0, stream>>>(pole_logits, zero_logits,
                                            poles_all, zeros_all,
                                            tpoles, tzeros, tnp, tnz, partials, B);
    vltf_finalize<<<1, 1024, 0, stream>>>((const float4*)partials, units / 4,
                                          1.0f / (float)B, (float*)d_out);
}

// Round 5
// 109.159 us; speedup vs baseline: 1.0718x; 1.0362x over previous
//
#include <hip/hip_runtime.h>
#include <float.h>

#define NCNT 33   // count classes 0..32
#define NPTS 32   // max poles/zeros

typedef float f32x2 __attribute__((ext_vector_type(2)));

__device__ __forceinline__ f32x2 mk2(float a, float b) { f32x2 r; r.x = a; r.y = b; return r; }

// ---------- DPP helpers ----------
template<int CTRL, bool BC>
__device__ __forceinline__ int dpp_i(int old, int v) {
    return __builtin_amdgcn_update_dpp(old, v, CTRL, 0xF, 0xF, BC);
}

// full-wave (64) sum; result broadcast to all lanes via readlane 63
__device__ __forceinline__ float wave_sum63(float v) {
    v += __int_as_float(dpp_i<0x111, true>(0, __float_as_int(v))); // row_shr:1
    v += __int_as_float(dpp_i<0x112, true>(0, __float_as_int(v))); // row_shr:2
    v += __int_as_float(dpp_i<0x114, true>(0, __float_as_int(v))); // row_shr:4
    v += __int_as_float(dpp_i<0x118, true>(0, __float_as_int(v))); // row_shr:8
    v += __int_as_float(dpp_i<0x142, true>(0, __float_as_int(v))); // row_bcast:15
    v += __int_as_float(dpp_i<0x143, true>(0, __float_as_int(v))); // row_bcast:31
    return __int_as_float(__builtin_amdgcn_readlane(__float_as_int(v), 63));
}

// full-wave max; result broadcast (uniform). bound_ctrl=false + old=v so
// out-of-range source lanes contribute fmax(v,v)=v.
__device__ __forceinline__ float wave_max63(float v) {
#define MX_STEP(C)                                                                    \
    {                                                                                 \
        int o = dpp_i<C, false>(__float_as_int(v), __float_as_int(v));                \
        v = fmaxf(v, __int_as_float(o));                                              \
    }
    MX_STEP(0x111) MX_STEP(0x112) MX_STEP(0x114) MX_STEP(0x118) MX_STEP(0x142) MX_STEP(0x143)
#undef MX_STEP
    return __int_as_float(__builtin_amdgcn_readlane(__float_as_int(v), 63));
}

// ---------- main kernel: one single-wave block per (row, part) unit ----------
// Round-0 shell (proven fastest) with two scheduling changes, NO arithmetic changes:
//  1. No __syncthreads(): single-wave block; intra-wave LDS RAW is ordered by the
//     compiler's lgkmcnt waits (pattern validated on-harness in round 4, absmax 0.0).
//     The barrier forced a full vmcnt/lgkmcnt drain and blocked code motion between
//     the CE chain and the staging/chamfer LDS traffic.
//  2. Staging split: tgt-side (u,v,s) validity depends only on nt (a load), so tgt
//     lanes stage IMMEDIATELY; pred-side needs np, so pred lanes stage right after
//     the ballot. The sume/log chain then overlaps ds_write->ds_read latency.
// LDS (floats): tgt UV [0..63], tgt S [64..95], pred UV [96..159], pred S [160..191]
// UV float4 j = (u_{2j}, u_{2j+1}, v_{2j}, v_{2j+1}); u=-2x, v=-2y, s=|pt|^2 (1e30 invalid)
__global__ __launch_bounds__(64) void vltf_kernel(
    const float* __restrict__ pole_logits, const float* __restrict__ zero_logits,
    const float* __restrict__ poles_all,   const float* __restrict__ zeros_all,
    const float* __restrict__ tpoles,      const float* __restrict__ tzeros,
    const int* __restrict__ tnum_p,        const int* __restrict__ tnum_z,
    float* __restrict__ partials)
{
    __shared__ __align__(16) float myl[192];

    const int lane = threadIdx.x;     // 0..63
    const int unit = blockIdx.x;
    const int row  = unit >> 1;
    const int part = unit & 1;

    const float* logits = part ? zero_logits : pole_logits;
    const float* predp  = part ? zeros_all   : poles_all;
    const float* tgtp   = part ? tzeros      : tpoles;
    const int*   tnum   = part ? tnum_z      : tnum_p;

    // ---- issue all global loads up front ----
    float x = (lane < NCNT) ? logits[row * NCNT + lane] : -FLT_MAX;
    const bool isPred = lane < 32;
    const int  idx    = lane & 31;
    const float2* ownArr = (const float2*)(isPred ? predp : tgtp);
    const float2  Pt     = ownArr[row * NPTS + idx];
    const int  nt = tnum[row];                    // target count (uniform)

    const float sreal = fmaf(Pt.x, Pt.x, Pt.y * Pt.y);
    const int wbase = isPred ? 96 : 0;
    const int uvpos = wbase + ((idx >> 1) << 2) + (idx & 1);

    // ---- tgt lanes stage immediately (validity from nt only) ----
    if (!isPred) {
        const bool vt = idx < nt;
        myl[uvpos]            = vt ? -2.f * Pt.x : 0.f;
        myl[uvpos + 2]        = vt ? -2.f * Pt.y : 0.f;
        myl[wbase + 64 + idx] = vt ? sreal : 1e30f;
    }

    // ---- CE max + argmax (np gates pred staging) ----
    float vmax = wave_max63(x);
    unsigned long long bm = __ballot(lane < NCNT && x == vmax);
    const int np = (int)__builtin_ctzll(bm);      // first-max index == pred count (uniform)

    // ---- pred lanes stage now that np is known ----
    if (isPred) {
        const bool vp = idx < np;
        myl[uvpos]            = vp ? -2.f * Pt.x : 0.f;
        myl[uvpos + 2]        = vp ? -2.f * Pt.y : 0.f;
        myl[wbase + 64 + idx] = vp ? sreal : 1e30f;
    }
    // no barrier: single-wave block, LDS write->read ordered by lgkmcnt

    // ---- CE sum/log chain (independent of staging; overlaps LDS latency) ----
    float e = (lane < NCNT) ? __expf(x - vmax) : 0.f;
    float sume = wave_sum63(e);
    float xt = __int_as_float(__builtin_amdgcn_readlane(__float_as_int(x), nt));
    float nll = vmax + __logf(sume) - xt;

    // ---- chamfer: min over 32 "other" points, 4 points/iter via pk_fma ----
    const int rbase = isPred ? 0 : 96;            // pred lanes read tgt staging, vice versa
    const float4* UVo = (const float4*)(myl + rbase);
    const float4* So  = (const float4*)(myl + rbase + 64);
    const f32x2 Pxv = mk2(Pt.x, Pt.x);
    const f32x2 Pyv = mk2(Pt.y, Pt.y);
    float m = FLT_MAX;
#pragma unroll
    for (int i = 0; i < 8; ++i) {
        float4 uv0 = UVo[2 * i], uv1 = UVo[2 * i + 1];
        float4 s4  = So[i];
        f32x2 val0 = Pyv * mk2(uv0.z, uv0.w) + mk2(s4.x, s4.y);
        val0       = Pxv * mk2(uv0.x, uv0.y) + val0;
        f32x2 val1 = Pyv * mk2(uv1.z, uv1.w) + mk2(s4.z, s4.w);
        val1       = Pxv * mk2(uv1.x, uv1.y) + val1;
        m = fminf(m, fminf(val0.x, val0.y));      // v_min3_f32
        m = fminf(m, fminf(val1.x, val1.y));
    }

    // ---- per-lane term with wave-uniform special cases ----
    const int  nown = isPred ? np : nt;
    const bool vown = idx < nown;
    float T;
    if (np > 0 && nt > 0) {
        float inv_n = __builtin_amdgcn_rcpf((float)nown);
        T = vown ? (m + sreal) * inv_n : 0.f;     // |p|^2 folded in once
    } else if (np == 0 && nt == 0) {
        T = 0.f;
    } else if (np == 0) {                          // out = sum_tgt_sq
        T = (!isPred && vown) ? sreal : 0.f;
    } else {                                       // nt == 0 -> sum_pred_sq
        T = (isPred && vown) ? sreal : 0.f;
    }
    float cham = wave_sum63(T);

    if (lane == 0) partials[unit] = 5.f * nll + cham;
}

// ---------- finalize: sum 65536 partials (as 16384 float4), divide by B ----------
__global__ __launch_bounds__(1024) void vltf_finalize(
    const float4* __restrict__ p4, int n4, float invB, float* __restrict__ out)
{
    float s = 0.f;
    for (int i = threadIdx.x; i < n4; i += 1024) {
        float4 v = p4[i];
        s += (v.x + v.y) + (v.z + v.w);
    }
    s = wave_sum63(s);
    __shared__ float sh[16];
    if ((threadIdx.x & 63) == 0) sh[threadIdx.x >> 6] = s;
    __syncthreads();
    if (threadIdx.x == 0) {
        float t = 0.f;
#pragma unroll
        for (int i = 0; i < 16; ++i) t += sh[i];
        out[0] = t * invB;
    }
}

extern "C" void kernel_launch(void* const* d_in, const int* in_sizes, int n_in,
                              void* d_out, int out_size, void* d_ws, size_t ws_size,
                              hipStream_t stream) {
    const float* pole_logits = (const float*)d_in[0];
    const float* zero_logits = (const float*)d_in[1];
    const float* poles_all   = (const float*)d_in[2];
    const float* zeros_all   = (const float*)d_in[3];
    const float* tpoles      = (const float*)d_in[4];
    const float* tzeros      = (const float*)d_in[5];
    const int*   tnp         = (const int*)d_in[6];
    const int*   tnz         = (const int*)d_in[7];

    const int B     = in_sizes[6];       // 32768
    const int units = 2 * B;             // (row, part) units; one single-wave block each

    float* partials = (float*)d_ws;      // units * 4 bytes (256 KiB) of scratch

    vltf_kernel<<<units, 64, 0, stream>>>(pole_logits, zero_logits,
                                          poles_all, zeros_all,
                                          tpoles, tzeros, tnp, tnz, partials);
    vltf_finalize<<<1, 1024, 0, stream>>>((const float4*)partials, units / 4,
                                          1.0f / (float)B, (float*)d_out);
}